// Round 4
// baseline (314.632 us; speedup 1.0000x reference)
//
#include <hip/hip_runtime.h>
#include <math.h>
#include <stdint.h>

#define HW_N 2304
#define CB   384
#define HIDD 512
#define HID2 1024      // fused w1||s1
#define DD   128
#define KK   64
#define BATCH 32
#define M1   65
#define NTOK (BATCH * HW_N)   // 73728 flattened tokens
#define NORM_ARG 2368.0f

typedef __bf16 bf16;
typedef __bf16 bf16x8 __attribute__((ext_vector_type(8)));
typedef float  f32x4  __attribute__((ext_vector_type(4)));

__device__ __forceinline__ void gld16(void* lds, const void* g) {
    __builtin_amdgcn_global_load_lds(
        (const __attribute__((address_space(1))) uint32_t*)g,
        (__attribute__((address_space(3))) uint32_t*)lds, 16, 0, 0);
}

// ---------------------------------------------------------------------------
// x[b][CB][HW_N] f32 -> xT[b][HW_N][CB] bf16, all batches
// ---------------------------------------------------------------------------
__global__ __launch_bounds__(256)
void x_to_bf16T(const float* __restrict__ x, bf16* __restrict__ xT)
{
    const int b  = blockIdx.z;
    const int n0 = blockIdx.x * 64;
    const int c0 = blockIdx.y * 64;
    __shared__ float t[64][65];
    const int tx = threadIdx.x & 15, ty = threadIdx.x >> 4;
    const float* xb = x + (long)b * CB * HW_N;
    #pragma unroll
    for (int r = 0; r < 64; r += 16) {
        const float4 vv = *(const float4*)&xb[(long)(c0 + r + ty) * HW_N + n0 + tx * 4];
        t[r + ty][tx * 4 + 0] = vv.x; t[r + ty][tx * 4 + 1] = vv.y;
        t[r + ty][tx * 4 + 2] = vv.z; t[r + ty][tx * 4 + 3] = vv.w;
    }
    __syncthreads();
    bf16* ob = xT + (long)b * HW_N * CB;
    #pragma unroll
    for (int r = 0; r < 64; r += 16) {
        const int n = r + ty;
        union { bf16 h[4]; uint2 u2; } pk;
        pk.h[0] = (bf16)t[tx * 4 + 0][n]; pk.h[1] = (bf16)t[tx * 4 + 1][n];
        pk.h[2] = (bf16)t[tx * 4 + 2][n]; pk.h[3] = (bf16)t[tx * 4 + 3][n];
        *(uint2*)&ob[(long)(n0 + n) * CB + c0 + tx * 4] = pk.u2;
    }
}

__global__ __launch_bounds__(256)
void f2bf4(const float* __restrict__ in, bf16* __restrict__ out, int n4)
{
    int i = blockIdx.x * 256 + threadIdx.x;
    if (i < n4) {
        float4 vv = ((const float4*)in)[i];
        union { bf16 h[4]; uint2 u2; } pk;
        pk.h[0] = (bf16)vv.x; pk.h[1] = (bf16)vv.y;
        pk.h[2] = (bf16)vv.z; pk.h[3] = (bf16)vv.w;
        ((uint2*)out)[i] = pk.u2;
    }
}

__global__ __launch_bounds__(256)
void concat_bias(const float* __restrict__ b1, const float* __restrict__ c1,
                 float* __restrict__ bc)
{
    int i = blockIdx.x * 256 + threadIdx.x;
    if (i < HIDD) bc[i] = b1[i];
    else if (i < HID2) bc[i] = c1[i - HIDD];
}

// ---------------------------------------------------------------------------
// Generic MFMA GEMM over k-major operands, bank-conflict-free LDS:
//   OUT(ra, rb) = act( A[ra][:K] . B[rb][:K] + bias )
// LDS tile [rows][32 bf16]; 16B slot s of row r holds global k-slot
// j = s ^ c(r), c(r) = (r + (r>>2)) & 3.  gld_lds writes linearly, so the
// swizzle is applied to the GLOBAL source per lane and inverted on the
// ds_read (rule: both-sides-or-neither). Tile-base rows are %16 so c(r)
// reduces to per-lane constants on both sides (zero inner-loop cost).
// OUT_MODE 0: OUT[rb][ra] bf16, row stride ldo (bias on ra, packed along ra)
// OUT_MODE 1: ra = global token -> (b, n); OUT[((b*ldo)+rb)*HW_N + n] bf16
// OUT_MODE 2: same addressing, f32 (bias on rb for modes 1/2)
// ---------------------------------------------------------------------------
template<int FA, int FB, int OUT_MODE, bool RELU, bool SWIZZLE>
__global__ __launch_bounds__(256)
void mfma_gemm(const bf16* __restrict__ A, int lda,
               const bf16* __restrict__ B, int ldb,
               const float* __restrict__ bias,
               void* __restrict__ OUT, int ldo,
               int K, int nA)
{
    constexpr int BA = FA * 32;
    constexpr int BB = FB * 32;
    __shared__ __align__(16) bf16 As[BA * 32];
    __shared__ __align__(16) bf16 Bs[BB * 32];

    int L = blockIdx.x;
    if (SWIZZLE) { const int cpx = gridDim.x >> 3; L = (L & 7) * cpx + (L >> 3); }
    const int ta = L % nA;
    const int tb = L / nA;

    const int tid  = threadIdx.x;
    const int lane = tid & 63;
    const int w    = tid >> 6;
    const int wr   = w >> 1, wc = w & 1;

    const bf16* Ap = A + (long)ta * BA * lda;
    const bf16* Bp = B + (long)tb * BB * ldb;

    f32x4 acc[FA][FB];
    #pragma unroll
    for (int i = 0; i < FA; i++)
        #pragma unroll
        for (int j = 0; j < FB; j++)
            acc[i][j] = (f32x4){0.f, 0.f, 0.f, 0.f};

    // staging-side swizzle: lane covers row rowq, LDS slot (lane&3);
    // global k-slot = (lane&3) ^ cS, cS = (rowq + rowq>>2) & 3
    const int rowq = lane >> 2;
    const int cS   = (rowq + (rowq >> 2)) & 3;
    const int colb = ((lane & 3) ^ cS) * 16;

    // read-side swizzle: row = (mult of 16) + (lane&15); k-slot wanted =
    // lane>>4; LDS slot = (lane>>4) ^ cL, cL = ((lane&15) + (lane&15)>>2) & 3
    const int rl = lane & 15;
    const int cL = (rl + (rl >> 2)) & 3;
    const int kslot = ((lane >> 4) ^ cL) * 8;   // bf16 units

    for (int k0 = 0; k0 < K; k0 += 32) {
        #pragma unroll
        for (int t = 0; t < BA / 64; t++) {
            const int ii = t * 4 + w;
            gld16((char*)As + ii * 1024,
                  (const char*)(Ap + (long)(ii * 16 + rowq) * lda + k0) + colb);
        }
        #pragma unroll
        for (int t = 0; t < BB / 64; t++) {
            const int ii = t * 4 + w;
            gld16((char*)Bs + ii * 1024,
                  (const char*)(Bp + (long)(ii * 16 + rowq) * ldb + k0) + colb);
        }
        __syncthreads();

        bf16x8 a[FA], bb[FB];
        #pragma unroll
        for (int i = 0; i < FA; i++)
            a[i] = *(const bf16x8*)(As + (wr * FA * 16 + i * 16 + rl) * 32 + kslot);
        #pragma unroll
        for (int j = 0; j < FB; j++)
            bb[j] = *(const bf16x8*)(Bs + (wc * FB * 16 + j * 16 + rl) * 32 + kslot);

        #pragma unroll
        for (int i = 0; i < FA; i++)
            #pragma unroll
            for (int j = 0; j < FB; j++)
                acc[i][j] = __builtin_amdgcn_mfma_f32_16x16x32_bf16(a[i], bb[j], acc[i][j], 0, 0, 0);
        __syncthreads();
    }

    const int fr = lane & 15;
    const int fq = lane >> 4;

    if (OUT_MODE == 0) {
        #pragma unroll
        for (int i = 0; i < FA; i++) {
            const int ra0 = ta * BA + wr * FA * 16 + i * 16 + fq * 4;
            const float4 bv = *(const float4*)&bias[ra0];
            #pragma unroll
            for (int j = 0; j < FB; j++) {
                const int rb = tb * BB + wc * FB * 16 + j * 16 + fr;
                union { bf16 h[4]; uint2 u2; } pk;
                float v0 = acc[i][j][0] + bv.x, v1 = acc[i][j][1] + bv.y;
                float v2 = acc[i][j][2] + bv.z, v3 = acc[i][j][3] + bv.w;
                if (RELU) {
                    v0 = fmaxf(v0, 0.f); v1 = fmaxf(v1, 0.f);
                    v2 = fmaxf(v2, 0.f); v3 = fmaxf(v3, 0.f);
                }
                pk.h[0] = (bf16)v0; pk.h[1] = (bf16)v1;
                pk.h[2] = (bf16)v2; pk.h[3] = (bf16)v3;
                *(uint2*)&((bf16*)OUT)[(long)rb * ldo + ra0] = pk.u2;
            }
        }
    } else {
        #pragma unroll
        for (int i = 0; i < FA; i++) {
            const int g0 = ta * BA + wr * FA * 16 + i * 16 + fq * 4;
            const int bi = g0 / HW_N;
            const int nn = g0 - bi * HW_N;
            #pragma unroll
            for (int j = 0; j < FB; j++) {
                const int mg = tb * BB + wc * FB * 16 + j * 16 + fr;
                const float bvs = bias[mg];
                float v0 = acc[i][j][0] + bvs, v1 = acc[i][j][1] + bvs;
                float v2 = acc[i][j][2] + bvs, v3 = acc[i][j][3] + bvs;
                if (RELU) {
                    v0 = fmaxf(v0, 0.f); v1 = fmaxf(v1, 0.f);
                    v2 = fmaxf(v2, 0.f); v3 = fmaxf(v3, 0.f);
                }
                const long base = ((long)bi * ldo + mg) * HW_N + nn;
                if (OUT_MODE == 1) {
                    union { bf16 h[4]; uint2 u2; } pk;
                    pk.h[0] = (bf16)v0; pk.h[1] = (bf16)v1;
                    pk.h[2] = (bf16)v2; pk.h[3] = (bf16)v3;
                    *(uint2*)&((bf16*)OUT)[base] = pk.u2;
                } else {
                    *(float4*)&((float*)OUT)[base] = make_float4(v0, v1, v2, v3);
                }
            }
        }
    }
}

// ---------------------------------------------------------------------------
// Sinkhorn passes (dust row analytic). Z[b][64][HW_N] f32.
// ---------------------------------------------------------------------------
template<bool FIRST>
__global__ __launch_bounds__(256)
void sink_u(const float* __restrict__ Z, const float* __restrict__ v,
            const float* __restrict__ alpha, float* __restrict__ u)
{
    const int b = blockIdx.y;
    const int i = blockIdx.x * 4 + (threadIdx.x >> 6);
    if (i > KK) return;
    const int lane = threadIdx.x & 63;
    const float* zr = Z + ((long)b * KK + i) * HW_N;
    const float* vb = v + (long)b * HW_N;
    const float a = alpha[0];
    float m = -INFINITY, s = 0.f;
    for (int j = lane; j < HW_N; j += 64) {
        float val = (i < KK) ? zr[j] : a;
        if (!FIRST) val += vb[j];
        float mn = fmaxf(m, val);
        s = s * __expf(m - mn) + __expf(val - mn);
        m = mn;
    }
    #pragma unroll
    for (int off = 32; off; off >>= 1) {
        float m2 = __shfl_xor(m, off), s2 = __shfl_xor(s, off);
        float mn = fmaxf(m, m2);
        s = s * __expf(m - mn) + s2 * __expf(m2 - mn);
        m = mn;
    }
    if (lane == 0) {
        const float norm = -logf(NORM_ARG);
        const float logmu = (i < KK) ? norm : (logf((float)(HW_N - KK)) + norm);
        u[b * M1 + i] = logmu - (m + __logf(s));
    }
}

__global__ __launch_bounds__(64)
void sink_v(const float* __restrict__ Z, const float* __restrict__ u,
            const float* __restrict__ alpha, float* __restrict__ v)
{
    const int b = blockIdx.y;
    const int n = blockIdx.x * 64 + threadIdx.x;
    const float* ub = u + b * M1;
    const float* Zb = Z + (long)b * KK * HW_N;
    float m = alpha[0] + ub[KK];
    float s = 1.f;
    for (int i = 0; i < KK; i++) {
        float t = Zb[(long)i * HW_N + n] + ub[i];
        float mn = fmaxf(m, t);
        s = s * __expf(m - mn) + __expf(t - mn);
        m = mn;
    }
    const float norm = -logf(NORM_ARG);
    v[(long)b * HW_N + n] = norm - (m + __logf(s));
}

// ---------------------------------------------------------------------------
// Pooling partials + finalize
// ---------------------------------------------------------------------------
__global__ __launch_bounds__(256)
void agg_partial(const bf16* __restrict__ f, const float* __restrict__ Z,
                 const float* __restrict__ u, const float* __restrict__ v,
                 float* __restrict__ part)
{
    const int c = blockIdx.x;
    const int b = blockIdx.y;
    const int n0 = c << 8;
    const float norm = -logf(NORM_ARG);

    __shared__ float Fs[16][132];
    __shared__ float Ps[16][68];

    const bf16*  fb = f + (long)b * DD * HW_N;
    const float* Zb = Z + (long)b * KK * HW_N;
    const float* ub = u + b * M1;
    const float* vb = v + (long)b * HW_N;

    const int tid = threadIdx.x;
    const int td = tid & 31;
    const int tk = tid >> 5;

    float acc[4][8] = {};

    for (int nt = 0; nt < 256; nt += 16) {
        #pragma unroll
        for (int i = 0; i < 8; i++) {
            int li = tid + (i << 8);
            int d = li >> 4, nn = li & 15;
            Fs[nn][d] = (float)fb[(long)d * HW_N + n0 + nt + nn];
        }
        #pragma unroll
        for (int i = 0; i < 4; i++) {
            int li = tid + (i << 8);
            int k = li >> 4, nn = li & 15;
            int n = n0 + nt + nn;
            Ps[nn][k] = __expf(Zb[(long)k * HW_N + n] + ub[k] + vb[n] - norm);
        }
        __syncthreads();
        #pragma unroll
        for (int nn = 0; nn < 16; nn++) {
            const float4 av = *reinterpret_cast<const float4*>(&Fs[nn][td << 2]);
            const float4 p0 = *reinterpret_cast<const float4*>(&Ps[nn][tk << 3]);
            const float4 p1 = *reinterpret_cast<const float4*>(&Ps[nn][(tk << 3) + 4]);
            float a[4] = {av.x, av.y, av.z, av.w};
            float p[8] = {p0.x, p0.y, p0.z, p0.w, p1.x, p1.y, p1.z, p1.w};
            #pragma unroll
            for (int i = 0; i < 4; i++)
                #pragma unroll
                for (int j = 0; j < 8; j++)
                    acc[i][j] += a[i] * p[j];
        }
        __syncthreads();
    }

    float* pb = part + (long)(b * 9 + c) * (DD * KK);
    #pragma unroll
    for (int i = 0; i < 4; i++) {
        int d = (td << 2) + i;
        float4 o0 = make_float4(acc[i][0], acc[i][1], acc[i][2], acc[i][3]);
        float4 o1 = make_float4(acc[i][4], acc[i][5], acc[i][6], acc[i][7]);
        *reinterpret_cast<float4*>(&pb[d * KK + (tk << 3)]) = o0;
        *reinterpret_cast<float4*>(&pb[d * KK + (tk << 3) + 4]) = o1;
    }
}

__global__ __launch_bounds__(256)
void finalize(const float* __restrict__ part, float* __restrict__ out)
{
    const int b = blockIdx.x;
    __shared__ float agg[DD * KK];
    __shared__ float nrm[KK];
    const int tid = threadIdx.x;

    for (int idx = tid; idx < DD * KK; idx += 256) {
        float s = 0.f;
        #pragma unroll
        for (int cc = 0; cc < 9; cc++)
            s += part[(long)(b * 9 + cc) * (DD * KK) + idx];
        agg[idx] = s;
    }
    __syncthreads();
    if (tid < KK) {
        float ss = 0.f;
        for (int d = 0; d < DD; d++) { float t = agg[d * KK + tid]; ss += t * t; }
        nrm[tid] = fmaxf(sqrtf(ss), 1e-12f);
    }
    __syncthreads();
    for (int idx = tid; idx < DD * KK; idx += 256)
        out[(long)b * (DD * KK) + idx] = agg[idx] / nrm[idx & 63];
}

// ---------------------------------------------------------------------------
extern "C" void kernel_launch(void* const* d_in, const int* in_sizes, int n_in,
                              void* d_out, int out_size, void* d_ws, size_t ws_size,
                              hipStream_t stream)
{
    const float* x     = (const float*)d_in[0];
    const float* w1    = (const float*)d_in[1];
    const float* b1    = (const float*)d_in[2];
    const float* w2    = (const float*)d_in[3];
    const float* b2    = (const float*)d_in[4];
    const float* s1    = (const float*)d_in[5];
    const float* c1    = (const float*)d_in[6];
    const float* s2    = (const float*)d_in[7];
    const float* c2    = (const float*)d_in[8];
    const float* alpha = (const float*)d_in[9];
    float* out = (float*)d_out;

    char* p = (char*)d_ws;
    bf16* Wc  = (bf16*)p;  p += (long)HID2 * CB * 2;
    bf16* w2b = (bf16*)p;  p += (long)DD * HIDD * 2;
    bf16* s2b = (bf16*)p;  p += (long)KK * HIDD * 2;
    float* bc = (float*)p; p += (long)HID2 * 4;
    bf16* xT  = (bf16*)p;  p += (long)NTOK * CB * 2;
    bf16* hs  = (bf16*)p;  p += (long)NTOK * HID2 * 2;
    bf16* f   = (bf16*)p;  p += (long)BATCH * DD * HW_N * 2;
    float* Z  = (float*)p; p += (long)BATCH * KK * HW_N * 4;
    float* u  = (float*)p; p += (long)BATCH * M1 * 4;
    float* v  = (float*)p; p += (long)BATCH * HW_N * 4;
    float* part = (float*)p;

    f2bf4<<<(HIDD * CB / 4 + 255) / 256, 256, 0, stream>>>(w1, Wc, HIDD * CB / 4);
    f2bf4<<<(HIDD * CB / 4 + 255) / 256, 256, 0, stream>>>(s1, Wc + (long)HIDD * CB, HIDD * CB / 4);
    f2bf4<<<(DD * HIDD / 4 + 255) / 256, 256, 0, stream>>>(w2, w2b, DD * HIDD / 4);
    f2bf4<<<(KK * HIDD / 4 + 255) / 256, 256, 0, stream>>>(s2, s2b, KK * HIDD / 4);
    concat_bias<<<4, 256, 0, stream>>>(b1, c1, bc);

    x_to_bf16T<<<dim3(36, 6, 32), 256, 0, stream>>>(x, xT);

    // stage 1 (fused w1||s1): hs[g][1024] = relu(xT @ Wc^T + bc)
    mfma_gemm<4, 4, 0, true, true><<<(HID2 / 128) * (NTOK / 128), 256, 0, stream>>>(
        Wc, CB, xT, CB, bc, hs, HID2, CB, HID2 / 128);

    // stage 2a: f[b][d][n] = hs[:, 0:512] @ w2^T + b2
    mfma_gemm<4, 4, 1, false, false><<<NTOK / 128, 256, 0, stream>>>(
        hs, HID2, w2b, HIDD, b2, f, DD, HIDD, NTOK / 128);

    // stage 2b: Z[b][k][n] = hs[:, 512:1024] @ s2^T + c2
    mfma_gemm<4, 2, 2, false, false><<<NTOK / 128, 256, 0, stream>>>(
        hs + HIDD, HID2, s2b, HIDD, c2, Z, KK, HIDD, NTOK / 128);

    sink_u<true ><<<dim3(17, 32), 256, 0, stream>>>(Z, v, alpha, u);
    sink_v<<<dim3(36, 32), 64, 0, stream>>>(Z, u, alpha, v);
    sink_u<false><<<dim3(17, 32), 256, 0, stream>>>(Z, v, alpha, u);
    sink_v<<<dim3(36, 32), 64, 0, stream>>>(Z, u, alpha, v);
    sink_u<false><<<dim3(17, 32), 256, 0, stream>>>(Z, v, alpha, u);
    sink_v<<<dim3(36, 32), 64, 0, stream>>>(Z, u, alpha, v);

    agg_partial<<<dim3(9, 32), 256, 0, stream>>>(f, Z, u, v, part);
    finalize<<<32, 256, 0, stream>>>(part, out);
}

// Round 5
// 306.485 us; speedup vs baseline: 1.0266x; 1.0266x over previous
//
#include <hip/hip_runtime.h>
#include <math.h>
#include <stdint.h>

#define HW_N 2304
#define CB   384
#define HIDD 512
#define HID2 1024      // fused w1||s1
#define DD   128
#define KK   64
#define BATCH 32
#define M1   65
#define NTOK (BATCH * HW_N)   // 73728 flattened tokens
#define NORM_ARG 2368.0f

typedef __bf16 bf16;
typedef __bf16 bf16x8 __attribute__((ext_vector_type(8)));
typedef float  f32x4  __attribute__((ext_vector_type(4)));

__device__ __forceinline__ void gld16(void* lds, const void* g) {
    __builtin_amdgcn_global_load_lds(
        (const __attribute__((address_space(1))) uint32_t*)g,
        (__attribute__((address_space(3))) uint32_t*)lds, 16, 0, 0);
}

// ---------------------------------------------------------------------------
// x[b][CB][HW_N] f32 -> xT[b][HW_N][CB] bf16, all batches
// ---------------------------------------------------------------------------
__global__ __launch_bounds__(256)
void x_to_bf16T(const float* __restrict__ x, bf16* __restrict__ xT)
{
    const int b  = blockIdx.z;
    const int n0 = blockIdx.x * 64;
    const int c0 = blockIdx.y * 64;
    __shared__ float t[64][65];
    const int tx = threadIdx.x & 15, ty = threadIdx.x >> 4;
    const float* xb = x + (long)b * CB * HW_N;
    #pragma unroll
    for (int r = 0; r < 64; r += 16) {
        const float4 vv = *(const float4*)&xb[(long)(c0 + r + ty) * HW_N + n0 + tx * 4];
        t[r + ty][tx * 4 + 0] = vv.x; t[r + ty][tx * 4 + 1] = vv.y;
        t[r + ty][tx * 4 + 2] = vv.z; t[r + ty][tx * 4 + 3] = vv.w;
    }
    __syncthreads();
    bf16* ob = xT + (long)b * HW_N * CB;
    #pragma unroll
    for (int r = 0; r < 64; r += 16) {
        const int n = r + ty;
        union { bf16 h[4]; uint2 u2; } pk;
        pk.h[0] = (bf16)t[tx * 4 + 0][n]; pk.h[1] = (bf16)t[tx * 4 + 1][n];
        pk.h[2] = (bf16)t[tx * 4 + 2][n]; pk.h[3] = (bf16)t[tx * 4 + 3][n];
        *(uint2*)&ob[(long)(n0 + n) * CB + c0 + tx * 4] = pk.u2;
    }
}

__global__ __launch_bounds__(256)
void f2bf4(const float* __restrict__ in, bf16* __restrict__ out, int n4)
{
    int i = blockIdx.x * 256 + threadIdx.x;
    if (i < n4) {
        float4 vv = ((const float4*)in)[i];
        union { bf16 h[4]; uint2 u2; } pk;
        pk.h[0] = (bf16)vv.x; pk.h[1] = (bf16)vv.y;
        pk.h[2] = (bf16)vv.z; pk.h[3] = (bf16)vv.w;
        ((uint2*)out)[i] = pk.u2;
    }
}

__global__ __launch_bounds__(256)
void concat_bias(const float* __restrict__ b1, const float* __restrict__ c1,
                 float* __restrict__ bc)
{
    int i = blockIdx.x * 256 + threadIdx.x;
    if (i < HIDD) bc[i] = b1[i];
    else if (i < HID2) bc[i] = c1[i - HIDD];
}

// ---------------------------------------------------------------------------
// Generic MFMA GEMM over k-major operands, 2-phase double-buffered staging:
//   OUT(ra, rb) = act( A[ra][:K] . B[rb][:K] + bias )
// Pattern (T3-min): STAGE(buf0); barrier; loop { STAGE(buf^1, t+1);
// ds_read buf; MFMA; barrier } — the vmcnt(0) the compiler emits at the
// barrier waits on NEXT tile's loads, which had the whole MFMA phase to
// land. One barrier per K-step instead of two.
// NOTE: SQ_LDS_BANK_CONFLICT ≈ 8/gld16 is the DMA write pattern itself
// (linear lane*16, measured invariant r3/r4) — not addressable in source.
// OUT_MODE 0: OUT[rb][ra] bf16, row stride ldo (bias on ra, packed along ra)
// OUT_MODE 1: ra = global token -> (b, n); OUT[((b*ldo)+rb)*HW_N + n] bf16
// OUT_MODE 2: same addressing, f32 (bias on rb for modes 1/2)
// ---------------------------------------------------------------------------
template<int FA, int FB, int OUT_MODE, bool RELU, bool SWIZZLE>
__global__ __launch_bounds__(256)
void mfma_gemm(const bf16* __restrict__ A, int lda,
               const bf16* __restrict__ B, int ldb,
               const float* __restrict__ bias,
               void* __restrict__ OUT, int ldo,
               int K, int nA)
{
    constexpr int BA = FA * 32;
    constexpr int BB = FB * 32;
    __shared__ __align__(16) bf16 As[2][BA * 32];
    __shared__ __align__(16) bf16 Bs[2][BB * 32];

    int L = blockIdx.x;
    if (SWIZZLE) { const int cpx = gridDim.x >> 3; L = (L & 7) * cpx + (L >> 3); }
    const int ta = L % nA;
    const int tb = L / nA;

    const int tid  = threadIdx.x;
    const int lane = tid & 63;
    const int w    = tid >> 6;
    const int wr   = w >> 1, wc = w & 1;

    const bf16* Ap = A + (long)ta * BA * lda;
    const bf16* Bp = B + (long)tb * BB * ldb;

    f32x4 acc[FA][FB];
    #pragma unroll
    for (int i = 0; i < FA; i++)
        #pragma unroll
        for (int j = 0; j < FB; j++)
            acc[i][j] = (f32x4){0.f, 0.f, 0.f, 0.f};

    const int rowq = lane >> 2;          // 0..15
    const int colb = (lane & 3) * 16;    // 16B slot within 64B k-row
    const int rl   = lane & 15;
    const int kslot = (lane >> 4) * 8;   // bf16 units

    const int nsteps = K / 32;

    // prologue: stage tile 0
    #pragma unroll
    for (int t = 0; t < BA / 64; t++) {
        const int ii = t * 4 + w;
        gld16((char*)As[0] + ii * 1024,
              (const char*)(Ap + (long)(ii * 16 + rowq) * lda) + colb);
    }
    #pragma unroll
    for (int t = 0; t < BB / 64; t++) {
        const int ii = t * 4 + w;
        gld16((char*)Bs[0] + ii * 1024,
              (const char*)(Bp + (long)(ii * 16 + rowq) * ldb) + colb);
    }
    __syncthreads();

    for (int t = 0; t < nsteps; ++t) {
        const int cur = t & 1;
        if (t + 1 < nsteps) {            // stage NEXT tile first (overlaps MFMA)
            const int k0 = (t + 1) * 32;
            #pragma unroll
            for (int s = 0; s < BA / 64; s++) {
                const int ii = s * 4 + w;
                gld16((char*)As[cur ^ 1] + ii * 1024,
                      (const char*)(Ap + (long)(ii * 16 + rowq) * lda + k0) + colb);
            }
            #pragma unroll
            for (int s = 0; s < BB / 64; s++) {
                const int ii = s * 4 + w;
                gld16((char*)Bs[cur ^ 1] + ii * 1024,
                      (const char*)(Bp + (long)(ii * 16 + rowq) * ldb + k0) + colb);
            }
        }

        bf16x8 a[FA], bb[FB];
        #pragma unroll
        for (int i = 0; i < FA; i++)
            a[i] = *(const bf16x8*)(As[cur] + (wr * FA * 16 + i * 16 + rl) * 32 + kslot);
        #pragma unroll
        for (int j = 0; j < FB; j++)
            bb[j] = *(const bf16x8*)(Bs[cur] + (wc * FB * 16 + j * 16 + rl) * 32 + kslot);

        #pragma unroll
        for (int i = 0; i < FA; i++)
            #pragma unroll
            for (int j = 0; j < FB; j++)
                acc[i][j] = __builtin_amdgcn_mfma_f32_16x16x32_bf16(a[i], bb[j], acc[i][j], 0, 0, 0);

        __syncthreads();   // drains vmcnt(0): next tile's loads landed under MFMA
    }

    const int fr = lane & 15;
    const int fq = lane >> 4;

    if (OUT_MODE == 0) {
        #pragma unroll
        for (int i = 0; i < FA; i++) {
            const int ra0 = ta * BA + wr * FA * 16 + i * 16 + fq * 4;
            const float4 bv = *(const float4*)&bias[ra0];
            #pragma unroll
            for (int j = 0; j < FB; j++) {
                const int rb = tb * BB + wc * FB * 16 + j * 16 + fr;
                union { bf16 h[4]; uint2 u2; } pk;
                float v0 = acc[i][j][0] + bv.x, v1 = acc[i][j][1] + bv.y;
                float v2 = acc[i][j][2] + bv.z, v3 = acc[i][j][3] + bv.w;
                if (RELU) {
                    v0 = fmaxf(v0, 0.f); v1 = fmaxf(v1, 0.f);
                    v2 = fmaxf(v2, 0.f); v3 = fmaxf(v3, 0.f);
                }
                pk.h[0] = (bf16)v0; pk.h[1] = (bf16)v1;
                pk.h[2] = (bf16)v2; pk.h[3] = (bf16)v3;
                *(uint2*)&((bf16*)OUT)[(long)rb * ldo + ra0] = pk.u2;
            }
        }
    } else {
        #pragma unroll
        for (int i = 0; i < FA; i++) {
            const int g0 = ta * BA + wr * FA * 16 + i * 16 + fq * 4;
            const int bi = g0 / HW_N;
            const int nn = g0 - bi * HW_N;
            #pragma unroll
            for (int j = 0; j < FB; j++) {
                const int mg = tb * BB + wc * FB * 16 + j * 16 + fr;
                const float bvs = bias[mg];
                float v0 = acc[i][j][0] + bvs, v1 = acc[i][j][1] + bvs;
                float v2 = acc[i][j][2] + bvs, v3 = acc[i][j][3] + bvs;
                if (RELU) {
                    v0 = fmaxf(v0, 0.f); v1 = fmaxf(v1, 0.f);
                    v2 = fmaxf(v2, 0.f); v3 = fmaxf(v3, 0.f);
                }
                const long base = ((long)bi * ldo + mg) * HW_N + nn;
                if (OUT_MODE == 1) {
                    union { bf16 h[4]; uint2 u2; } pk;
                    pk.h[0] = (bf16)v0; pk.h[1] = (bf16)v1;
                    pk.h[2] = (bf16)v2; pk.h[3] = (bf16)v3;
                    *(uint2*)&((bf16*)OUT)[base] = pk.u2;
                } else {
                    *(float4*)&((float*)OUT)[base] = make_float4(v0, v1, v2, v3);
                }
            }
        }
    }
}

// ---------------------------------------------------------------------------
// Sinkhorn passes (dust row analytic). Z[b][64][HW_N] f32.
// ---------------------------------------------------------------------------
template<bool FIRST>
__global__ __launch_bounds__(256)
void sink_u(const float* __restrict__ Z, const float* __restrict__ v,
            const float* __restrict__ alpha, float* __restrict__ u)
{
    const int b = blockIdx.y;
    const int i = blockIdx.x * 4 + (threadIdx.x >> 6);
    if (i > KK) return;
    const int lane = threadIdx.x & 63;
    const float* zr = Z + ((long)b * KK + i) * HW_N;
    const float* vb = v + (long)b * HW_N;
    const float a = alpha[0];
    float m = -INFINITY, s = 0.f;
    for (int j = lane; j < HW_N; j += 64) {
        float val = (i < KK) ? zr[j] : a;
        if (!FIRST) val += vb[j];
        float mn = fmaxf(m, val);
        s = s * __expf(m - mn) + __expf(val - mn);
        m = mn;
    }
    #pragma unroll
    for (int off = 32; off; off >>= 1) {
        float m2 = __shfl_xor(m, off), s2 = __shfl_xor(s, off);
        float mn = fmaxf(m, m2);
        s = s * __expf(m - mn) + s2 * __expf(m2 - mn);
        m = mn;
    }
    if (lane == 0) {
        const float norm = -logf(NORM_ARG);
        const float logmu = (i < KK) ? norm : (logf((float)(HW_N - KK)) + norm);
        u[b * M1 + i] = logmu - (m + __logf(s));
    }
}

__global__ __launch_bounds__(64)
void sink_v(const float* __restrict__ Z, const float* __restrict__ u,
            const float* __restrict__ alpha, float* __restrict__ v)
{
    const int b = blockIdx.y;
    const int n = blockIdx.x * 64 + threadIdx.x;
    const float* ub = u + b * M1;
    const float* Zb = Z + (long)b * KK * HW_N;
    float m = alpha[0] + ub[KK];
    float s = 1.f;
    for (int i = 0; i < KK; i++) {
        float t = Zb[(long)i * HW_N + n] + ub[i];
        float mn = fmaxf(m, t);
        s = s * __expf(m - mn) + __expf(t - mn);
        m = mn;
    }
    const float norm = -logf(NORM_ARG);
    v[(long)b * HW_N + n] = norm - (m + __logf(s));
}

// ---------------------------------------------------------------------------
// Pooling partials + finalize
// ---------------------------------------------------------------------------
__global__ __launch_bounds__(256)
void agg_partial(const bf16* __restrict__ f, const float* __restrict__ Z,
                 const float* __restrict__ u, const float* __restrict__ v,
                 float* __restrict__ part)
{
    const int c = blockIdx.x;
    const int b = blockIdx.y;
    const int n0 = c << 8;
    const float norm = -logf(NORM_ARG);

    __shared__ float Fs[16][132];
    __shared__ float Ps[16][68];

    const bf16*  fb = f + (long)b * DD * HW_N;
    const float* Zb = Z + (long)b * KK * HW_N;
    const float* ub = u + b * M1;
    const float* vb = v + (long)b * HW_N;

    const int tid = threadIdx.x;
    const int td = tid & 31;
    const int tk = tid >> 5;

    float acc[4][8] = {};

    for (int nt = 0; nt < 256; nt += 16) {
        #pragma unroll
        for (int i = 0; i < 8; i++) {
            int li = tid + (i << 8);
            int d = li >> 4, nn = li & 15;
            Fs[nn][d] = (float)fb[(long)d * HW_N + n0 + nt + nn];
        }
        #pragma unroll
        for (int i = 0; i < 4; i++) {
            int li = tid + (i << 8);
            int k = li >> 4, nn = li & 15;
            int n = n0 + nt + nn;
            Ps[nn][k] = __expf(Zb[(long)k * HW_N + n] + ub[k] + vb[n] - norm);
        }
        __syncthreads();
        #pragma unroll
        for (int nn = 0; nn < 16; nn++) {
            const float4 av = *reinterpret_cast<const float4*>(&Fs[nn][td << 2]);
            const float4 p0 = *reinterpret_cast<const float4*>(&Ps[nn][tk << 3]);
            const float4 p1 = *reinterpret_cast<const float4*>(&Ps[nn][(tk << 3) + 4]);
            float a[4] = {av.x, av.y, av.z, av.w};
            float p[8] = {p0.x, p0.y, p0.z, p0.w, p1.x, p1.y, p1.z, p1.w};
            #pragma unroll
            for (int i = 0; i < 4; i++)
                #pragma unroll
                for (int j = 0; j < 8; j++)
                    acc[i][j] += a[i] * p[j];
        }
        __syncthreads();
    }

    float* pb = part + (long)(b * 9 + c) * (DD * KK);
    #pragma unroll
    for (int i = 0; i < 4; i++) {
        int d = (td << 2) + i;
        float4 o0 = make_float4(acc[i][0], acc[i][1], acc[i][2], acc[i][3]);
        float4 o1 = make_float4(acc[i][4], acc[i][5], acc[i][6], acc[i][7]);
        *reinterpret_cast<float4*>(&pb[d * KK + (tk << 3)]) = o0;
        *reinterpret_cast<float4*>(&pb[d * KK + (tk << 3) + 4]) = o1;
    }
}

__global__ __launch_bounds__(256)
void finalize(const float* __restrict__ part, float* __restrict__ out)
{
    const int b = blockIdx.x;
    __shared__ float agg[DD * KK];
    __shared__ float nrm[KK];
    const int tid = threadIdx.x;

    for (int idx = tid; idx < DD * KK; idx += 256) {
        float s = 0.f;
        #pragma unroll
        for (int cc = 0; cc < 9; cc++)
            s += part[(long)(b * 9 + cc) * (DD * KK) + idx];
        agg[idx] = s;
    }
    __syncthreads();
    if (tid < KK) {
        float ss = 0.f;
        for (int d = 0; d < DD; d++) { float t = agg[d * KK + tid]; ss += t * t; }
        nrm[tid] = fmaxf(sqrtf(ss), 1e-12f);
    }
    __syncthreads();
    for (int idx = tid; idx < DD * KK; idx += 256)
        out[(long)b * (DD * KK) + idx] = agg[idx] / nrm[idx & 63];
}

// ---------------------------------------------------------------------------
extern "C" void kernel_launch(void* const* d_in, const int* in_sizes, int n_in,
                              void* d_out, int out_size, void* d_ws, size_t ws_size,
                              hipStream_t stream)
{
    const float* x     = (const float*)d_in[0];
    const float* w1    = (const float*)d_in[1];
    const float* b1    = (const float*)d_in[2];
    const float* w2    = (const float*)d_in[3];
    const float* b2    = (const float*)d_in[4];
    const float* s1    = (const float*)d_in[5];
    const float* c1    = (const float*)d_in[6];
    const float* s2    = (const float*)d_in[7];
    const float* c2    = (const float*)d_in[8];
    const float* alpha = (const float*)d_in[9];
    float* out = (float*)d_out;

    char* p = (char*)d_ws;
    bf16* Wc  = (bf16*)p;  p += (long)HID2 * CB * 2;
    bf16* w2b = (bf16*)p;  p += (long)DD * HIDD * 2;
    bf16* s2b = (bf16*)p;  p += (long)KK * HIDD * 2;
    float* bc = (float*)p; p += (long)HID2 * 4;
    bf16* xT  = (bf16*)p;  p += (long)NTOK * CB * 2;
    bf16* hs  = (bf16*)p;  p += (long)NTOK * HID2 * 2;
    bf16* f   = (bf16*)p;  p += (long)BATCH * DD * HW_N * 2;
    float* Z  = (float*)p; p += (long)BATCH * KK * HW_N * 4;
    float* u  = (float*)p; p += (long)BATCH * M1 * 4;
    float* v  = (float*)p; p += (long)BATCH * HW_N * 4;
    float* part = (float*)p;

    f2bf4<<<(HIDD * CB / 4 + 255) / 256, 256, 0, stream>>>(w1, Wc, HIDD * CB / 4);
    f2bf4<<<(HIDD * CB / 4 + 255) / 256, 256, 0, stream>>>(s1, Wc + (long)HIDD * CB, HIDD * CB / 4);
    f2bf4<<<(DD * HIDD / 4 + 255) / 256, 256, 0, stream>>>(w2, w2b, DD * HIDD / 4);
    f2bf4<<<(KK * HIDD / 4 + 255) / 256, 256, 0, stream>>>(s2, s2b, KK * HIDD / 4);
    concat_bias<<<4, 256, 0, stream>>>(b1, c1, bc);

    x_to_bf16T<<<dim3(36, 6, 32), 256, 0, stream>>>(x, xT);

    // stage 1 (fused w1||s1): hs[g][1024] = relu(xT @ Wc^T + bc)
    mfma_gemm<4, 4, 0, true, true><<<(HID2 / 128) * (NTOK / 128), 256, 0, stream>>>(
        Wc, CB, xT, CB, bc, hs, HID2, CB, HID2 / 128);

    // stage 2a: f[b][d][n] = hs[:, 0:512] @ w2^T + b2
    mfma_gemm<4, 4, 1, false, false><<<NTOK / 128, 256, 0, stream>>>(
        hs, HID2, w2b, HIDD, b2, f, DD, HIDD, NTOK / 128);

    // stage 2b: Z[b][k][n] = hs[:, 512:1024] @ s2^T + c2
    mfma_gemm<4, 2, 2, false, false><<<NTOK / 128, 256, 0, stream>>>(
        hs + HIDD, HID2, s2b, HIDD, c2, Z, KK, HIDD, NTOK / 128);

    sink_u<true ><<<dim3(17, 32), 256, 0, stream>>>(Z, v, alpha, u);
    sink_v<<<dim3(36, 32), 64, 0, stream>>>(Z, u, alpha, v);
    sink_u<false><<<dim3(17, 32), 256, 0, stream>>>(Z, v, alpha, u);
    sink_v<<<dim3(36, 32), 64, 0, stream>>>(Z, u, alpha, v);
    sink_u<false><<<dim3(17, 32), 256, 0, stream>>>(Z, v, alpha, u);
    sink_v<<<dim3(36, 32), 64, 0, stream>>>(Z, u, alpha, v);

    agg_partial<<<dim3(9, 32), 256, 0, stream>>>(f, Z, u, v, part);
    finalize<<<32, 256, 0, stream>>>(part, out);
}